// Round 1
// baseline (285.072 us; speedup 1.0000x reference)
//
#include <hip/hip_runtime.h>
#include <cstdint>

#define FARV 1e10f

constexpr int NC  = 256;   // coarse samples per ray
constexpr int NS  = 128;   // importance samples per ray
constexpr int NF  = 384;   // fine samples per ray
constexpr int RPB = 4;     // rays (waves) per block

__device__ __forceinline__ float wave_incl_scan_prod(float v, int lane) {
  float x = v;
#pragma unroll
  for (int off = 1; off < 64; off <<= 1) {
    float o = __shfl_up(x, off);
    if (lane >= off) x *= o;
  }
  return x;
}

__device__ __forceinline__ float wave_incl_scan_add(float v, int lane) {
  float x = v;
#pragma unroll
  for (int off = 1; off < 64; off <<= 1) {
    float o = __shfl_up(x, off);
    if (lane >= off) x += o;
  }
  return x;
}

__device__ __forceinline__ int wave_incl_scan_addi(int v, int lane) {
  int x = v;
#pragma unroll
  for (int off = 1; off < 64; off <<= 1) {
    int o = __shfl_up(x, off);
    if (lane >= off) x += o;
  }
  return x;
}

__device__ __forceinline__ float wave_reduce(float v) {
#pragma unroll
  for (int off = 32; off; off >>= 1) v += __shfl_down(v, off);
  return v;
}

// first index in arr[0..n) with arr[idx] > u  (== count of elements <= u)
__device__ __forceinline__ int upper_bound_lds(const float* arr, int n, float u) {
  int lo = 0;
  while (n > 0) {
    int h = n >> 1;
    int mid = lo + h;
    if (arr[mid] <= u) { lo = mid + 1; n -= h + 1; }
    else n = h;
  }
  return lo;
}

__global__ __launch_bounds__(256) void vr_kernel(
    const float* __restrict__ z_vals,
    const float* __restrict__ density,
    const float* __restrict__ feature,
    const float* __restrict__ fine_density,
    const float* __restrict__ fine_feature,
    const float* __restrict__ u_rand,
    float* __restrict__ out)
{
  __shared__ __align__(16) float zv[RPB][NC];        // coarse z (sorted)
  __shared__ __align__(16) float cdfs[RPB][NC];      // 255 entries used
  __shared__ __align__(16) int   Hh[RPB][NC];        // histogram of sample insertion idx
  __shared__ __align__(16) float zf[RPB][NF];        // merged sorted fine z
  __shared__ __align__(16) float ffs[RPB][NF * 3];   // staged fine_feature

  const int wid  = threadIdx.x >> 6;
  const int lane = threadIdx.x & 63;
  const int ray  = blockIdx.x * RPB + wid;

  // ---- stage fine_feature to LDS early (latency hides under coarse pass) ----
  {
    const float* src = fine_feature + (size_t)ray * (NF * 3);
#pragma unroll
    for (int r = 0; r < 4; ++r) {
      const int idx = r * 64 + lane;
      const float4 v = *(const float4*)(src + idx * 4);
      *(float4*)(&ffs[wid][idx * 4]) = v;
    }
    if (lane < 32) {
      const int idx = 256 + lane;
      const float4 v = *(const float4*)(src + idx * 4);
      *(float4*)(&ffs[wid][idx * 4]) = v;
    }
  }
  // zero histogram
  *(int4*)(&Hh[wid][lane * 4]) = make_int4(0, 0, 0, 0);

  // ---------------- coarse pass (4 samples / lane) ----------------
  const float4 z4 = *(const float4*)(z_vals  + (size_t)ray * NC + lane * 4);
  const float4 d4 = *(const float4*)(density + (size_t)ray * NC + lane * 4);
  const float4 fA = *(const float4*)(feature + (size_t)ray * NC * 3 + lane * 12);
  const float4 fB = *(const float4*)(feature + (size_t)ray * NC * 3 + lane * 12 + 4);
  const float4 fC = *(const float4*)(feature + (size_t)ray * NC * 3 + lane * 12 + 8);

  *(float4*)(&zv[wid][lane * 4]) = z4;

  const float znext = __shfl_down(z4.x, 1);
  const float dl0 = z4.y - z4.x;
  const float dl1 = z4.z - z4.y;
  const float dl2 = z4.w - z4.z;
  const float dl3 = (lane == 63) ? FARV : (znext - z4.w);

  const float e0 = __expf(-d4.x * dl0);
  const float e1 = __expf(-d4.y * dl1);
  const float e2 = __expf(-d4.z * dl2);
  const float e3 = __expf(-d4.w * dl3);

  const float p1 = e0, p2 = e0 * e1, p3 = p2 * e2, ptot = p3 * e3;
  const float incl = wave_incl_scan_prod(ptot, lane);
  float Tb = __shfl_up(incl, 1);
  if (lane == 0) Tb = 1.0f;

  const float w0 = Tb *      (1.0f - e0) + 1e-10f;
  const float w1 = Tb * p1 * (1.0f - e1) + 1e-10f;
  const float w2 = Tb * p2 * (1.0f - e2) + 1e-10f;
  const float w3 = Tb * p3 * (1.0f - e3) + 1e-10f;

  // feature layout per lane: fA={f0.xyz,f1.x} fB={f1.yz,f2.xy} fC={f2.z,f3.xyz}
  float fx = w0 * fA.x + w1 * fA.w + w2 * fB.z + w3 * fC.y;
  float fy = w0 * fA.y + w1 * fB.x + w2 * fB.w + w3 * fC.z;
  float fz = w0 * fA.z + w1 * fB.y + w2 * fC.x + w3 * fC.w;
  float dep = w0 * z4.x + w1 * z4.y + w2 * z4.z + w3 * z4.w;

  // ---------------- CDF over w[1:255] (254 entries) ----------------
  const float wn0 = __shfl_down(w0, 1);   // next lane's w0
  const bool l63 = (lane == 63);
  const float m0 = w1 + 1e-5f;                   // w_mid idx 4l+0
  const float m1 = w2 + 1e-5f;                   // 4l+1
  const float m2 = l63 ? 0.0f : (w3 + 1e-5f);    // 4l+2 (invalid for lane63)
  const float m3 = l63 ? 0.0f : (wn0 + 1e-5f);   // 4l+3 (invalid for lane63)
  const float c1 = m0 + m1;
  const float c2 = c1 + m2;
  const float c3 = c2 + m3;
  const float inclS = wave_incl_scan_add(c3, lane);
  float Sb = __shfl_up(inclS, 1);
  if (lane == 0) Sb = 0.0f;
  const float total = __shfl(inclS, 63);
  const float inv = 1.0f / total;

  cdfs[wid][4 * lane + 1] = (Sb + m0) * inv;
  cdfs[wid][4 * lane + 2] = (Sb + c1) * inv;
  if (!l63) {
    cdfs[wid][4 * lane + 3] = (Sb + c2) * inv;
    cdfs[wid][4 * lane + 4] = (Sb + c3) * inv;
  }
  if (lane == 0) cdfs[wid][0] = 0.0f;

  __syncthreads();

  // ---------------- importance sampling (2 u's / lane) ----------------
  const float2 uu = *(const float2*)(u_rand + (size_t)ray * NS + lane * 2);

  float s[2]; int up[2];
  const float u2[2] = {uu.x, uu.y};
#pragma unroll
  for (int t = 0; t < 2; ++t) {
    const float u = u2[t];
    const int ind = upper_bound_lds(&cdfs[wid][0], 255, u);  // in [1,255]
    const int below = (ind > 0) ? ind - 1 : 0;
    const int above = (ind < 254) ? ind : 254;
    const float cb = cdfs[wid][below];
    const float ca = cdfs[wid][above];
    const float bb = 0.5f * (zv[wid][below] + zv[wid][below + 1]);
    const float ba = 0.5f * (zv[wid][above] + zv[wid][above + 1]);
    float den = ca - cb;
    den = (den < 1e-5f) ? 1.0f : den;
    const float tt = (u - cb) / den;
    s[t] = bb + tt * (ba - bb);
    // insertion position among coarse z (count zv <= s); clamp for safety
    int u_ = upper_bound_lds(&zv[wid][0], 256, s[t]);
    up[t] = (u_ > 255) ? 255 : u_;
    atomicAdd(&Hh[wid][up[t]], 1);
  }

  // among-samples rank: all-pairs over the wave's 128 samples via shuffles
  const float sA = s[0], sB = s[1];
  int cA = 0, cB = 0;
#pragma unroll 4
  for (int k = 0; k < 64; ++k) {
    const float a = __shfl(sA, k);   // sample index 2k
    const float b = __shfl(sB, k);   // sample index 2k+1
    const bool kl = (k < lane);
    cA += (a < sA || (a == sA && kl)) ? 1 : 0;
    cA += (b < sA || (b == sA && kl)) ? 1 : 0;
    cB += (a < sB || (a == sB && (kl || k == lane))) ? 1 : 0;
    cB += (b < sB || (b == sB && kl)) ? 1 : 0;
  }
  // scatter samples into merged array
  zf[wid][up[0] + cA] = sA;
  zf[wid][up[1] + cB] = sB;

  __syncthreads();

  // z ranks: i + inclusive-prefix of histogram at i
  const int4 h4 = *(const int4*)(&Hh[wid][4 * lane]);
  const int t0 = h4.x;
  const int t1 = t0 + h4.y;
  const int t2 = t1 + h4.z;
  const int t3 = t2 + h4.w;
  const int inclH = wave_incl_scan_addi(t3, lane);
  int Hb = __shfl_up(inclH, 1);
  if (lane == 0) Hb = 0;

  zf[wid][4 * lane + 0 + Hb + t0] = z4.x;
  zf[wid][4 * lane + 1 + Hb + t1] = z4.y;
  zf[wid][4 * lane + 2 + Hb + t2] = z4.z;
  zf[wid][4 * lane + 3 + Hb + t3] = z4.w;

  __syncthreads();

  // ---------------- fine pass (6 samples / lane) ----------------
  const int p0 = 6 * lane;
  float zq[7];
#pragma unroll
  for (int j = 0; j < 6; ++j) zq[j] = zf[wid][p0 + j];
  zq[6] = (lane < 63) ? zf[wid][p0 + 6] : 0.0f;

  float dlf[6];
#pragma unroll
  for (int j = 0; j < 5; ++j) dlf[j] = zq[j + 1] - zq[j];
  dlf[5] = (lane == 63) ? FARV : (zq[6] - zq[5]);

  const float* fd = fine_density + (size_t)ray * NF + p0;
  const float2 q0 = *(const float2*)(fd);
  const float2 q1 = *(const float2*)(fd + 2);
  const float2 q2 = *(const float2*)(fd + 4);
  const float fdv[6] = {q0.x, q0.y, q1.x, q1.y, q2.x, q2.y};

  float ee[6];
#pragma unroll
  for (int j = 0; j < 6; ++j) ee[j] = __expf(-fdv[j] * dlf[j]);

  float P[6];
  P[0] = 1.0f;
#pragma unroll
  for (int j = 1; j < 6; ++j) P[j] = P[j - 1] * ee[j - 1];
  const float ftot = P[5] * ee[5];

  const float incF = wave_incl_scan_prod(ftot, lane);
  float Tb2 = __shfl_up(incF, 1);
  if (lane == 0) Tb2 = 1.0f;

  float gx = 0.0f, gy = 0.0f, gz = 0.0f, fdep = 0.0f;
#pragma unroll
  for (int j = 0; j < 6; ++j) {
    const float wf = Tb2 * P[j] * (1.0f - ee[j]) + 1e-10f;
    gx += wf * ffs[wid][18 * lane + 3 * j + 0];
    gy += wf * ffs[wid][18 * lane + 3 * j + 1];
    gz += wf * ffs[wid][18 * lane + 3 * j + 2];
    fdep += wf * zq[j];
  }

  // ---------------- reductions + output ----------------
  fx = wave_reduce(fx);
  fy = wave_reduce(fy);
  fz = wave_reduce(fz);
  dep = wave_reduce(dep);
  gx = wave_reduce(gx);
  gy = wave_reduce(gy);
  gz = wave_reduce(gz);
  fdep = wave_reduce(fdep);

  if (lane == 0) {
    float* o = out + (size_t)ray * 8;
    *(float4*)(o)     = make_float4(fx, fy, fz, dep);
    *(float4*)(o + 4) = make_float4(gx, gy, gz, fdep);
  }
}

extern "C" void kernel_launch(void* const* d_in, const int* in_sizes, int n_in,
                              void* d_out, int out_size, void* d_ws, size_t ws_size,
                              hipStream_t stream) {
  const float* z_vals       = (const float*)d_in[0];
  const float* density      = (const float*)d_in[1];
  const float* feature      = (const float*)d_in[2];
  const float* fine_density = (const float*)d_in[3];
  const float* fine_feature = (const float*)d_in[4];
  const float* u_rand       = (const float*)d_in[5];
  float* out = (float*)d_out;

  const int B = in_sizes[0] / NC;       // 65536
  dim3 grid(B / RPB), block(RPB * 64);
  hipLaunchKernelGGL(vr_kernel, grid, block, 0, stream,
                     z_vals, density, feature, fine_density, fine_feature,
                     u_rand, out);
}

// Round 2
// 197.810 us; speedup vs baseline: 1.4411x; 1.4411x over previous
//
#include <hip/hip_runtime.h>
#include <cstdint>

#define FARV 1e10f

constexpr int NC  = 256;   // coarse samples per ray
constexpr int NS  = 128;   // importance samples per ray
constexpr int NF  = 384;   // fine samples per ray
constexpr int RPB = 4;     // rays (waves) per block

__device__ __forceinline__ float wave_incl_scan_prod(float v, int lane) {
  float x = v;
#pragma unroll
  for (int off = 1; off < 64; off <<= 1) {
    float o = __shfl_up(x, off);
    if (lane >= off) x *= o;
  }
  return x;
}

__device__ __forceinline__ float wave_incl_scan_add(float v, int lane) {
  float x = v;
#pragma unroll
  for (int off = 1; off < 64; off <<= 1) {
    float o = __shfl_up(x, off);
    if (lane >= off) x += o;
  }
  return x;
}

__device__ __forceinline__ int wave_incl_scan_addi(int v, int lane) {
  int x = v;
#pragma unroll
  for (int off = 1; off < 64; off <<= 1) {
    int o = __shfl_up(x, off);
    if (lane >= off) x += o;
  }
  return x;
}

__device__ __forceinline__ float wave_reduce(float v) {
#pragma unroll
  for (int off = 32; off; off >>= 1) v += __shfl_down(v, off);
  return v;
}

// first index in arr[0..n) with arr[idx] > u  (== count of elements <= u)
__device__ __forceinline__ int upper_bound_lds(const float* arr, int n, float u) {
  int lo = 0;
  while (n > 0) {
    int h = n >> 1;
    int mid = lo + h;
    if (arr[mid] <= u) { lo = mid + 1; n -= h + 1; }
    else n = h;
  }
  return lo;
}

__global__ __launch_bounds__(256, 8) void vr_kernel(
    const float* __restrict__ z_vals,
    const float* __restrict__ density,
    const float* __restrict__ feature,
    const float* __restrict__ fine_density,
    const float* __restrict__ fine_feature,
    const float* __restrict__ u_rand,
    float* __restrict__ out)
{
  __shared__ __align__(16) float zv[RPB][NC];        // coarse z (sorted)
  __shared__ __align__(16) float cdfs[RPB][NC];      // 255 entries used
  __shared__ __align__(16) int   Hh[RPB][NC];        // histogram of sample insertion idx
  __shared__ __align__(16) float zf[RPB][NF];        // merged z; later reused for wf

  const int wid  = threadIdx.x >> 6;
  const int lane = threadIdx.x & 63;
  const int ray  = blockIdx.x * RPB + wid;

  // zero histogram
  *(int4*)(&Hh[wid][lane * 4]) = make_int4(0, 0, 0, 0);

  // ---------------- coarse pass (4 samples / lane) ----------------
  const float4 z4 = *(const float4*)(z_vals  + (size_t)ray * NC + lane * 4);
  const float4 d4 = *(const float4*)(density + (size_t)ray * NC + lane * 4);
  const float4 fA = *(const float4*)(feature + (size_t)ray * NC * 3 + lane * 12);
  const float4 fB = *(const float4*)(feature + (size_t)ray * NC * 3 + lane * 12 + 4);
  const float4 fC = *(const float4*)(feature + (size_t)ray * NC * 3 + lane * 12 + 8);

  *(float4*)(&zv[wid][lane * 4]) = z4;

  const float znext = __shfl_down(z4.x, 1);
  const float dl0 = z4.y - z4.x;
  const float dl1 = z4.z - z4.y;
  const float dl2 = z4.w - z4.z;
  const float dl3 = (lane == 63) ? FARV : (znext - z4.w);

  const float e0 = __expf(-d4.x * dl0);
  const float e1 = __expf(-d4.y * dl1);
  const float e2 = __expf(-d4.z * dl2);
  const float e3 = __expf(-d4.w * dl3);

  const float p1 = e0, p2 = e0 * e1, p3 = p2 * e2, ptot = p3 * e3;
  const float incl = wave_incl_scan_prod(ptot, lane);
  float Tb = __shfl_up(incl, 1);
  if (lane == 0) Tb = 1.0f;

  const float w0 = Tb *      (1.0f - e0) + 1e-10f;
  const float w1 = Tb * p1 * (1.0f - e1) + 1e-10f;
  const float w2 = Tb * p2 * (1.0f - e2) + 1e-10f;
  const float w3 = Tb * p3 * (1.0f - e3) + 1e-10f;

  // feature layout per lane: fA={f0.xyz,f1.x} fB={f1.yz,f2.xy} fC={f2.z,f3.xyz}
  float fx = w0 * fA.x + w1 * fA.w + w2 * fB.z + w3 * fC.y;
  float fy = w0 * fA.y + w1 * fB.x + w2 * fB.w + w3 * fC.z;
  float fz = w0 * fA.z + w1 * fB.y + w2 * fC.x + w3 * fC.w;
  float dep = w0 * z4.x + w1 * z4.y + w2 * z4.z + w3 * z4.w;

  // ---------------- CDF over w[1:255] (254 entries) ----------------
  const float wn0 = __shfl_down(w0, 1);   // next lane's w0
  const bool l63 = (lane == 63);
  const float m0 = w1 + 1e-5f;                   // w_mid idx 4l+0
  const float m1 = w2 + 1e-5f;                   // 4l+1
  const float m2 = l63 ? 0.0f : (w3 + 1e-5f);    // 4l+2 (invalid for lane63)
  const float m3 = l63 ? 0.0f : (wn0 + 1e-5f);   // 4l+3 (invalid for lane63)
  const float c1 = m0 + m1;
  const float c2 = c1 + m2;
  const float c3 = c2 + m3;
  const float inclS = wave_incl_scan_add(c3, lane);
  float Sb = __shfl_up(inclS, 1);
  if (lane == 0) Sb = 0.0f;
  const float total = __shfl(inclS, 63);
  const float inv = 1.0f / total;

  cdfs[wid][4 * lane + 1] = (Sb + m0) * inv;
  cdfs[wid][4 * lane + 2] = (Sb + c1) * inv;
  if (!l63) {
    cdfs[wid][4 * lane + 3] = (Sb + c2) * inv;
    cdfs[wid][4 * lane + 4] = (Sb + c3) * inv;
  }
  if (lane == 0) cdfs[wid][0] = 0.0f;

  __syncthreads();

  // ---------------- importance sampling (2 u's / lane) ----------------
  const float2 uu = *(const float2*)(u_rand + (size_t)ray * NS + lane * 2);

  float s[2]; int up[2];
  const float u2[2] = {uu.x, uu.y};
#pragma unroll
  for (int t = 0; t < 2; ++t) {
    const float u = u2[t];
    const int ind = upper_bound_lds(&cdfs[wid][0], 255, u);  // in [1,254]
    const int below = (ind > 0) ? ind - 1 : 0;
    const int above = (ind < 254) ? ind : 254;
    const float cb = cdfs[wid][below];
    const float ca = cdfs[wid][above];
    const float zb0 = zv[wid][below];
    const float zb1 = zv[wid][below + 1];
    const float zb2 = zv[wid][(below + 2 < 256) ? below + 2 : 255];
    const float bb = 0.5f * (zb0 + zb1);
    const float ba = 0.5f * (zb1 + zb2);   // z_mid[above] when above==below+1
    float den = ca - cb;
    den = (den < 1e-5f) ? 1.0f : den;
    const float tt = (u - cb) / den;
    s[t] = bb + tt * (ba - bb);
    // insertion position among coarse z: s in [zv[below], zv[below+2]]
    int u_ = below + 1 + ((s[t] >= zb1) ? 1 : 0) + ((s[t] >= zb2) ? 1 : 0);
    up[t] = (u_ > 255) ? 255 : u_;
    atomicAdd(&Hh[wid][up[t]], 1);
  }

  // among-samples rank: all-pairs over the wave's 128 samples via shuffles
  const float sA = s[0], sB = s[1];
  int cA = 0, cB = 0;
#pragma unroll 4
  for (int k = 0; k < 64; ++k) {
    const float a = __shfl(sA, k);   // sample index 2k
    const float b = __shfl(sB, k);   // sample index 2k+1
    const bool kl = (k < lane);
    cA += (a < sA || (a == sA && kl)) ? 1 : 0;
    cA += (b < sA || (b == sA && kl)) ? 1 : 0;
    cB += (a < sB || (a == sB && (kl || k == lane))) ? 1 : 0;
    cB += (b < sB || (b == sB && kl)) ? 1 : 0;
  }
  // scatter samples into merged array
  zf[wid][up[0] + cA] = sA;
  zf[wid][up[1] + cB] = sB;

  __syncthreads();

  // z ranks: i + inclusive-prefix of histogram at i
  const int4 h4 = *(const int4*)(&Hh[wid][4 * lane]);
  const int t0 = h4.x;
  const int t1 = t0 + h4.y;
  const int t2 = t1 + h4.z;
  const int t3 = t2 + h4.w;
  const int inclH = wave_incl_scan_addi(t3, lane);
  int Hb = __shfl_up(inclH, 1);
  if (lane == 0) Hb = 0;

  zf[wid][4 * lane + 0 + Hb + t0] = z4.x;
  zf[wid][4 * lane + 1 + Hb + t1] = z4.y;
  zf[wid][4 * lane + 2 + Hb + t2] = z4.z;
  zf[wid][4 * lane + 3 + Hb + t3] = z4.w;

  __syncthreads();

  // ---------------- fine pass (6 samples / lane, sample-major) ----------------
  const int p0 = 6 * lane;
  const float* zfp = &zf[wid][p0];
  const float2 zp0 = *(const float2*)(zfp);
  const float2 zp1 = *(const float2*)(zfp + 2);
  const float2 zp2 = *(const float2*)(zfp + 4);
  float zq[7];
  zq[0] = zp0.x; zq[1] = zp0.y; zq[2] = zp1.x; zq[3] = zp1.y;
  zq[4] = zp2.x; zq[5] = zp2.y;
  zq[6] = (lane < 63) ? zfp[6] : 0.0f;

  float dlf[6];
#pragma unroll
  for (int j = 0; j < 5; ++j) dlf[j] = zq[j + 1] - zq[j];
  dlf[5] = (lane == 63) ? FARV : (zq[6] - zq[5]);

  const float* fd = fine_density + (size_t)ray * NF + p0;
  const float2 q0 = *(const float2*)(fd);
  const float2 q1 = *(const float2*)(fd + 2);
  const float2 q2 = *(const float2*)(fd + 4);
  const float fdv[6] = {q0.x, q0.y, q1.x, q1.y, q2.x, q2.y};

  float ee[6];
#pragma unroll
  for (int j = 0; j < 6; ++j) ee[j] = __expf(-fdv[j] * dlf[j]);

  float P[6];
  P[0] = 1.0f;
#pragma unroll
  for (int j = 1; j < 6; ++j) P[j] = P[j - 1] * ee[j - 1];
  const float ftot = P[5] * ee[5];

  const float incF = wave_incl_scan_prod(ftot, lane);
  float Tb2 = __shfl_up(incF, 1);
  if (lane == 0) Tb2 = 1.0f;

  float wfv[6];
  float fdep = 0.0f;
#pragma unroll
  for (int j = 0; j < 6; ++j) {
    wfv[j] = Tb2 * P[j] * (1.0f - ee[j]) + 1e-10f;
    fdep += wfv[j] * zq[j];
  }

  // store wf into zf (zf contents fully consumed above; wave-private row)
  float* wfp = &zf[wid][p0];
  *(float2*)(wfp)     = make_float2(wfv[0], wfv[1]);
  *(float2*)(wfp + 2) = make_float2(wfv[2], wfv[3]);
  *(float2*)(wfp + 4) = make_float2(wfv[4], wfv[5]);

  __syncthreads();

  // ---------------- lane-major feature accumulation (coalesced global) ----------------
  float gx = 0.0f, gy = 0.0f, gz = 0.0f;
  const float* ffb = fine_feature + (size_t)ray * (NF * 3);
#pragma unroll
  for (int r = 0; r < 6; ++r) {
    const int idx = r * 64 + lane;
    const float w = zf[wid][idx];
    const float* fp = ffb + idx * 3;
    gx += w * fp[0];
    gy += w * fp[1];
    gz += w * fp[2];
  }

  // ---------------- reductions + output ----------------
  fx = wave_reduce(fx);
  fy = wave_reduce(fy);
  fz = wave_reduce(fz);
  dep = wave_reduce(dep);
  gx = wave_reduce(gx);
  gy = wave_reduce(gy);
  gz = wave_reduce(gz);
  fdep = wave_reduce(fdep);

  if (lane == 0) {
    float* o = out + (size_t)ray * 8;
    *(float4*)(o)     = make_float4(fx, fy, fz, dep);
    *(float4*)(o + 4) = make_float4(gx, gy, gz, fdep);
  }
}

extern "C" void kernel_launch(void* const* d_in, const int* in_sizes, int n_in,
                              void* d_out, int out_size, void* d_ws, size_t ws_size,
                              hipStream_t stream) {
  const float* z_vals       = (const float*)d_in[0];
  const float* density      = (const float*)d_in[1];
  const float* feature      = (const float*)d_in[2];
  const float* fine_density = (const float*)d_in[3];
  const float* fine_feature = (const float*)d_in[4];
  const float* u_rand       = (const float*)d_in[5];
  float* out = (float*)d_out;

  const int B = in_sizes[0] / NC;       // 65536
  dim3 grid(B / RPB), block(RPB * 64);
  hipLaunchKernelGGL(vr_kernel, grid, block, 0, stream,
                     z_vals, density, feature, fine_density, fine_feature,
                     u_rand, out);
}

// Round 3
// 142.402 us; speedup vs baseline: 2.0019x; 1.3891x over previous
//
#include <hip/hip_runtime.h>
#include <cstdint>

#define FARV 1e10f

constexpr int NC  = 256;   // coarse samples per ray
constexpr int NS  = 128;   // importance samples per ray
constexpr int NF  = 384;   // fine samples per ray
constexpr int RPB = 4;     // rays (waves) per block

__device__ __forceinline__ float wave_incl_scan_prod(float v, int lane) {
  float x = v;
#pragma unroll
  for (int off = 1; off < 64; off <<= 1) {
    float o = __shfl_up(x, off);
    if (lane >= off) x *= o;
  }
  return x;
}

__device__ __forceinline__ float wave_incl_scan_add(float v, int lane) {
  float x = v;
#pragma unroll
  for (int off = 1; off < 64; off <<= 1) {
    float o = __shfl_up(x, off);
    if (lane >= off) x += o;
  }
  return x;
}

__device__ __forceinline__ int wave_incl_scan_addi(int v, int lane) {
  int x = v;
#pragma unroll
  for (int off = 1; off < 64; off <<= 1) {
    int o = __shfl_up(x, off);
    if (lane >= off) x += o;
  }
  return x;
}

__device__ __forceinline__ float wave_reduce(float v) {
#pragma unroll
  for (int off = 32; off; off >>= 1) v += __shfl_down(v, off);
  return v;
}

// first index in arr[0..n) with arr[idx] > u  (== count of elements <= u)
__device__ __forceinline__ int upper_bound_lds(const float* arr, int n, float u) {
  int lo = 0;
  while (n > 0) {
    int h = n >> 1;
    int mid = lo + h;
    if (arr[mid] <= u) { lo = mid + 1; n -= h + 1; }
    else n = h;
  }
  return lo;
}

__device__ __forceinline__ void cmpswap_local(float& a, float& b, bool asc) {
  const float lo = fminf(a, b), hi = fmaxf(a, b);
  a = asc ? lo : hi;
  b = asc ? hi : lo;
}

__device__ __forceinline__ float cmpswap_xor(float v, int m, bool take_min) {
  const float p = __shfl_xor(v, m);
  return take_min ? fminf(v, p) : fmaxf(v, p);
}

// Bitonic sort of 128 floats held as 2/lane; element e = 2*lane + slot.
// After: v0 = sorted elem 2*lane, v1 = sorted elem 2*lane+1 (ascending).
__device__ __forceinline__ void bitonic_sort128(float& v0, float& v1, int lane) {
  {  // k = 2 (local pair)
    const bool asc = ((lane & 1) == 0);
    cmpswap_local(v0, v1, asc);
  }
#pragma unroll
  for (int k = 4; k <= 128; k <<= 1) {
    const int kh = k >> 1;
    const bool asc = ((lane & kh) == 0);
#pragma unroll
    for (int j = kh; j >= 2; j >>= 1) {
      const int m = j >> 1;
      const bool take_min = (((lane & m) == 0) == asc);
      v0 = cmpswap_xor(v0, m, take_min);
      v1 = cmpswap_xor(v1, m, take_min);
    }
    cmpswap_local(v0, v1, asc);  // j = 1
  }
}

__global__ __launch_bounds__(256, 8) void vr_kernel(
    const float* __restrict__ z_vals,
    const float* __restrict__ density,
    const float* __restrict__ feature,
    const float* __restrict__ fine_density,
    const float* __restrict__ fine_feature,
    const float* __restrict__ u_rand,
    float* __restrict__ out)
{
  __shared__ __align__(16) float zv[RPB][NC];        // coarse z (sorted)
  __shared__ __align__(16) float cdfs[RPB][NC];      // 255 entries used
  __shared__ __align__(16) int   Hh[RPB][NC];        // histogram of sample insertion idx
  __shared__ __align__(16) float zf[RPB][NF];        // merged z; later reused for wf

  const int wid  = threadIdx.x >> 6;
  const int lane = threadIdx.x & 63;
  const int ray  = blockIdx.x * RPB + wid;

  // zero histogram
  *(int4*)(&Hh[wid][lane * 4]) = make_int4(0, 0, 0, 0);

  // load u early (latency hides under coarse pass)
  const float2 uu = *(const float2*)(u_rand + (size_t)ray * NS + lane * 2);

  // ---------------- coarse pass (4 samples / lane) ----------------
  const float4 z4 = *(const float4*)(z_vals  + (size_t)ray * NC + lane * 4);
  const float4 d4 = *(const float4*)(density + (size_t)ray * NC + lane * 4);
  const float4 fA = *(const float4*)(feature + (size_t)ray * NC * 3 + lane * 12);
  const float4 fB = *(const float4*)(feature + (size_t)ray * NC * 3 + lane * 12 + 4);
  const float4 fC = *(const float4*)(feature + (size_t)ray * NC * 3 + lane * 12 + 8);

  *(float4*)(&zv[wid][lane * 4]) = z4;

  const float znext = __shfl_down(z4.x, 1);
  const float dl0 = z4.y - z4.x;
  const float dl1 = z4.z - z4.y;
  const float dl2 = z4.w - z4.z;
  const float dl3 = (lane == 63) ? FARV : (znext - z4.w);

  const float e0 = __expf(-d4.x * dl0);
  const float e1 = __expf(-d4.y * dl1);
  const float e2 = __expf(-d4.z * dl2);
  const float e3 = __expf(-d4.w * dl3);

  const float p1 = e0, p2 = e0 * e1, p3 = p2 * e2, ptot = p3 * e3;
  const float incl = wave_incl_scan_prod(ptot, lane);
  float Tb = __shfl_up(incl, 1);
  if (lane == 0) Tb = 1.0f;

  const float w0 = Tb *      (1.0f - e0) + 1e-10f;
  const float w1 = Tb * p1 * (1.0f - e1) + 1e-10f;
  const float w2 = Tb * p2 * (1.0f - e2) + 1e-10f;
  const float w3 = Tb * p3 * (1.0f - e3) + 1e-10f;

  // feature layout per lane: fA={f0.xyz,f1.x} fB={f1.yz,f2.xy} fC={f2.z,f3.xyz}
  float fx = w0 * fA.x + w1 * fA.w + w2 * fB.z + w3 * fC.y;
  float fy = w0 * fA.y + w1 * fB.x + w2 * fB.w + w3 * fC.z;
  float fz = w0 * fA.z + w1 * fB.y + w2 * fC.x + w3 * fC.w;
  float dep = w0 * z4.x + w1 * z4.y + w2 * z4.z + w3 * z4.w;

  // ---------------- CDF over w[1:255] (254 entries) ----------------
  const float wn0 = __shfl_down(w0, 1);   // next lane's w0
  const bool l63 = (lane == 63);
  const float m0 = w1 + 1e-5f;                   // w_mid idx 4l+0
  const float m1 = w2 + 1e-5f;                   // 4l+1
  const float m2 = l63 ? 0.0f : (w3 + 1e-5f);    // 4l+2 (invalid for lane63)
  const float m3 = l63 ? 0.0f : (wn0 + 1e-5f);   // 4l+3 (invalid for lane63)
  const float c1 = m0 + m1;
  const float c2 = c1 + m2;
  const float c3 = c2 + m3;
  const float inclS = wave_incl_scan_add(c3, lane);
  float Sb = __shfl_up(inclS, 1);
  if (lane == 0) Sb = 0.0f;
  const float total = __shfl(inclS, 63);
  const float inv = 1.0f / total;

  cdfs[wid][4 * lane + 1] = (Sb + m0) * inv;
  cdfs[wid][4 * lane + 2] = (Sb + c1) * inv;
  if (!l63) {
    cdfs[wid][4 * lane + 3] = (Sb + c2) * inv;
    cdfs[wid][4 * lane + 4] = (Sb + c3) * inv;
  }
  if (lane == 0) cdfs[wid][0] = 0.0f;

  // ---------------- sort the u's (rank of s == rank of u; s monotone in u) ----
  float v0 = uu.x, v1 = uu.y;
  bitonic_sort128(v0, v1, lane);   // lane holds sorted elems 2*lane, 2*lane+1

  __syncthreads();

  // ---------------- importance sampling on sorted u's (2 / lane) ----------------
#pragma unroll
  for (int t = 0; t < 2; ++t) {
    const float u = t ? v1 : v0;
    const int ind = upper_bound_lds(&cdfs[wid][0], 255, u);  // in [1,255]
    const int below = (ind > 0) ? ind - 1 : 0;
    const int above = (ind < 254) ? ind : 254;
    const float cb = cdfs[wid][below];
    const float ca = cdfs[wid][above];
    const float zb0 = zv[wid][below];
    const float zb1 = zv[wid][below + 1];
    const float zb2 = zv[wid][(below + 2 < 256) ? below + 2 : 255];
    const float bb = 0.5f * (zb0 + zb1);
    const float ba = 0.5f * (zb1 + zb2);   // z_mid[above] when above==below+1
    float den = ca - cb;
    den = (den < 1e-5f) ? 1.0f : den;
    const float tt = (u - cb) / den;
    const float s = bb + tt * (ba - bb);
    // insertion position among coarse z: s in [zv[below], zv[below+2]]
    int u_ = below + 1 + ((s >= zb1) ? 1 : 0) + ((s >= zb2) ? 1 : 0);
    const int up = (u_ > 255) ? 255 : u_;
    atomicAdd(&Hh[wid][up], 1);
    // among-samples rank == sorted index (s monotone in u)
    zf[wid][up + 2 * lane + t] = s;
  }

  __syncthreads();

  // z ranks: i + inclusive-prefix of histogram at i
  const int4 h4 = *(const int4*)(&Hh[wid][4 * lane]);
  const int t0 = h4.x;
  const int t1 = t0 + h4.y;
  const int t2 = t1 + h4.z;
  const int t3 = t2 + h4.w;
  const int inclH = wave_incl_scan_addi(t3, lane);
  int Hb = __shfl_up(inclH, 1);
  if (lane == 0) Hb = 0;

  zf[wid][4 * lane + 0 + Hb + t0] = z4.x;
  zf[wid][4 * lane + 1 + Hb + t1] = z4.y;
  zf[wid][4 * lane + 2 + Hb + t2] = z4.z;
  zf[wid][4 * lane + 3 + Hb + t3] = z4.w;

  __syncthreads();

  // ---------------- fine pass (6 samples / lane, sample-major) ----------------
  const int p0 = 6 * lane;
  const float* zfp = &zf[wid][p0];
  const float2 zp0 = *(const float2*)(zfp);
  const float2 zp1 = *(const float2*)(zfp + 2);
  const float2 zp2 = *(const float2*)(zfp + 4);
  float zq[7];
  zq[0] = zp0.x; zq[1] = zp0.y; zq[2] = zp1.x; zq[3] = zp1.y;
  zq[4] = zp2.x; zq[5] = zp2.y;
  zq[6] = (lane < 63) ? zfp[6] : 0.0f;

  float dlf[6];
#pragma unroll
  for (int j = 0; j < 5; ++j) dlf[j] = zq[j + 1] - zq[j];
  dlf[5] = (lane == 63) ? FARV : (zq[6] - zq[5]);

  const float* fd = fine_density + (size_t)ray * NF + p0;
  const float2 q0 = *(const float2*)(fd);
  const float2 q1 = *(const float2*)(fd + 2);
  const float2 q2 = *(const float2*)(fd + 4);
  const float fdv[6] = {q0.x, q0.y, q1.x, q1.y, q2.x, q2.y};

  float ee[6];
#pragma unroll
  for (int j = 0; j < 6; ++j) ee[j] = __expf(-fdv[j] * dlf[j]);

  float P[6];
  P[0] = 1.0f;
#pragma unroll
  for (int j = 1; j < 6; ++j) P[j] = P[j - 1] * ee[j - 1];
  const float ftot = P[5] * ee[5];

  const float incF = wave_incl_scan_prod(ftot, lane);
  float Tb2 = __shfl_up(incF, 1);
  if (lane == 0) Tb2 = 1.0f;

  float wfv[6];
  float fdep = 0.0f;
#pragma unroll
  for (int j = 0; j < 6; ++j) {
    wfv[j] = Tb2 * P[j] * (1.0f - ee[j]) + 1e-10f;
    fdep += wfv[j] * zq[j];
  }

  // store wf into zf (zf contents fully consumed above; wave-private row)
  float* wfp = &zf[wid][p0];
  *(float2*)(wfp)     = make_float2(wfv[0], wfv[1]);
  *(float2*)(wfp + 2) = make_float2(wfv[2], wfv[3]);
  *(float2*)(wfp + 4) = make_float2(wfv[4], wfv[5]);

  __syncthreads();

  // ---------------- lane-major feature accumulation (coalesced global) ----------------
  float gx = 0.0f, gy = 0.0f, gz = 0.0f;
  const float* ffb = fine_feature + (size_t)ray * (NF * 3);
#pragma unroll
  for (int r = 0; r < 6; ++r) {
    const int idx = r * 64 + lane;
    const float w = zf[wid][idx];
    const float* fp = ffb + idx * 3;
    gx += w * fp[0];
    gy += w * fp[1];
    gz += w * fp[2];
  }

  // ---------------- reductions + output ----------------
  fx = wave_reduce(fx);
  fy = wave_reduce(fy);
  fz = wave_reduce(fz);
  dep = wave_reduce(dep);
  gx = wave_reduce(gx);
  gy = wave_reduce(gy);
  gz = wave_reduce(gz);
  fdep = wave_reduce(fdep);

  if (lane == 0) {
    float* o = out + (size_t)ray * 8;
    *(float4*)(o)     = make_float4(fx, fy, fz, dep);
    *(float4*)(o + 4) = make_float4(gx, gy, gz, fdep);
  }
}

extern "C" void kernel_launch(void* const* d_in, const int* in_sizes, int n_in,
                              void* d_out, int out_size, void* d_ws, size_t ws_size,
                              hipStream_t stream) {
  const float* z_vals       = (const float*)d_in[0];
  const float* density      = (const float*)d_in[1];
  const float* feature      = (const float*)d_in[2];
  const float* fine_density = (const float*)d_in[3];
  const float* fine_feature = (const float*)d_in[4];
  const float* u_rand       = (const float*)d_in[5];
  float* out = (float*)d_out;

  const int B = in_sizes[0] / NC;       // 65536
  dim3 grid(B / RPB), block(RPB * 64);
  hipLaunchKernelGGL(vr_kernel, grid, block, 0, stream,
                     z_vals, density, feature, fine_density, fine_feature,
                     u_rand, out);
}

// Round 6
// 129.019 us; speedup vs baseline: 2.2095x; 1.1037x over previous
//
#include <hip/hip_runtime.h>
#include <cstdint>

#define FARV 1e10f

constexpr int NC  = 256;   // coarse samples per ray
constexpr int NS  = 128;   // importance samples per ray
constexpr int NF  = 384;   // fine samples per ray
constexpr int RPB = 4;     // rays (waves) per block
constexpr int ZFP = 400;   // padded zf row: phys = i + (i>>5), max 394

// ---------------- DPP helpers (gfx9 encodings, valid on gfx950) ----------------
// row_shr:N = 0x110|N, wave_shl1 = 0x130, wave_shr1 = 0x138,
// bcast15 = 0x142, bcast31 = 0x143, quad_perm = 0x00..0xFF
template<int CTRL, int RM, int BM>
__device__ __forceinline__ float dppf(float old, float x) {
  return __int_as_float(__builtin_amdgcn_update_dpp(
      __float_as_int(old), __float_as_int(x), CTRL, RM, BM, false));
}
template<int CTRL, int RM, int BM>
__device__ __forceinline__ int dppi(int old, int x) {
  return __builtin_amdgcn_update_dpp(old, x, CTRL, RM, BM, false);
}
template<int CTRL>
__device__ __forceinline__ float dppq(float x) {  // full permutation (quad_perm)
  return __int_as_float(__builtin_amdgcn_update_dpp(
      0, __float_as_int(x), CTRL, 0xf, 0xf, true));
}
template<int MASK>
__device__ __forceinline__ float swzx(float x) {  // xor swizzle within 32-lane halves
  return __int_as_float(__builtin_amdgcn_ds_swizzle(
      __float_as_int(x), (MASK << 10) | 0x1f));
}

__device__ __forceinline__ float scan_incl_mul(float x) {
  x *= dppf<0x111, 0xf, 0xf>(1.f, x);
  x *= dppf<0x112, 0xf, 0xf>(1.f, x);
  x *= dppf<0x114, 0xf, 0xf>(1.f, x);
  x *= dppf<0x118, 0xf, 0xf>(1.f, x);
  x *= dppf<0x142, 0xa, 0xf>(1.f, x);
  x *= dppf<0x143, 0xc, 0xf>(1.f, x);
  return x;
}
__device__ __forceinline__ float scan_incl_add(float x) {
  x += dppf<0x111, 0xf, 0xf>(0.f, x);
  x += dppf<0x112, 0xf, 0xf>(0.f, x);
  x += dppf<0x114, 0xf, 0xf>(0.f, x);
  x += dppf<0x118, 0xf, 0xf>(0.f, x);
  x += dppf<0x142, 0xa, 0xf>(0.f, x);
  x += dppf<0x143, 0xc, 0xf>(0.f, x);
  return x;
}
__device__ __forceinline__ int scan_incl_addi(int x) {
  x += dppi<0x111, 0xf, 0xf>(0, x);
  x += dppi<0x112, 0xf, 0xf>(0, x);
  x += dppi<0x114, 0xf, 0xf>(0, x);
  x += dppi<0x118, 0xf, 0xf>(0, x);
  x += dppi<0x142, 0xa, 0xf>(0, x);
  x += dppi<0x143, 0xc, 0xf>(0, x);
  return x;
}
__device__ __forceinline__ float wshr1(float x, float id) { return dppf<0x138, 0xf, 0xf>(id, x); }
__device__ __forceinline__ int   wshr1i(int x)            { return dppi<0x138, 0xf, 0xf>(0, x); }
__device__ __forceinline__ float wshl1(float x)           { return dppf<0x130, 0xf, 0xf>(0.f, x); }

__device__ __forceinline__ void cmpswap_local(float& a, float& b, bool asc) {
  const float lo = fminf(a, b), hi = fmaxf(a, b);
  a = asc ? lo : hi;
  b = asc ? hi : lo;
}

template<int M>
__device__ __forceinline__ float xpartner(float v) {
  if constexpr (M == 1)       return dppq<0xB1>(v);      // quad_perm [1,0,3,2]
  else if constexpr (M == 2)  return dppq<0x4E>(v);      // quad_perm [2,3,0,1]
  else if constexpr (M <= 16) return swzx<M>(v);
  else                        return __shfl_xor(v, M);
}
template<int M>
__device__ __forceinline__ void merge_down(float& v0, float& v1, bool asc, int lane) {
  const bool tm = ((lane & M) == 0) == asc;
  const float p0 = xpartner<M>(v0);
  const float p1 = xpartner<M>(v1);
  v0 = tm ? fminf(v0, p0) : fmaxf(v0, p0);
  v1 = tm ? fminf(v1, p1) : fmaxf(v1, p1);
  if constexpr (M > 1) merge_down<M / 2>(v0, v1, asc, lane);
}
template<int K>
__device__ __forceinline__ void bitonic_stage(float& v0, float& v1, int lane) {
  const bool asc = (lane & (K >> 1)) == 0;
  merge_down<K / 4>(v0, v1, asc, lane);
  cmpswap_local(v0, v1, asc);
}
// sort 128 floats, 2/lane, elem e = 2*lane+slot, ascending
__device__ __forceinline__ void bitonic_sort128(float& v0, float& v1, int lane) {
  cmpswap_local(v0, v1, (lane & 1) == 0);
  bitonic_stage<4>(v0, v1, lane);
  bitonic_stage<8>(v0, v1, lane);
  bitonic_stage<16>(v0, v1, lane);
  bitonic_stage<32>(v0, v1, lane);
  bitonic_stage<64>(v0, v1, lane);
  bitonic_stage<128>(v0, v1, lane);
}

__global__ __launch_bounds__(256, 8) void vr_kernel(
    const float* __restrict__ z_vals,
    const float* __restrict__ density,
    const float* __restrict__ feature,
    const float* __restrict__ fine_density,
    const float* __restrict__ fine_feature,
    const float* __restrict__ u_rand,
    float* __restrict__ out)
{
  // All rows are WAVE-PRIVATE ([wid]) -> no __syncthreads anywhere; per-wave
  // in-order DS execution + compiler lgkmcnt tracking give the ordering.
  __shared__ __align__(16) float zv[RPB][NC];     // coarse z (sorted)
  __shared__ __align__(16) float cdfs[RPB][NC];   // cdf[0..255], float4-written
  __shared__ __align__(16) float cdfg[RPB][64];   // group heads cdf[4g]
  __shared__ __align__(16) int   Hh[RPB][NC];     // histogram of insertion idx
  __shared__ __align__(16) float zf[RPB][ZFP];    // merged z (padded); later wf (unpadded)

  const int wid  = threadIdx.x >> 6;
  const int lane = threadIdx.x & 63;
  const int ray  = blockIdx.x * RPB + wid;

  float* const zfr = &zf[wid][0];

  // zero histogram
  *(int4*)(&Hh[wid][lane * 4]) = make_int4(0, 0, 0, 0);

  // load u early (latency hides under coarse pass)
  const float2 uu = *(const float2*)(u_rand + (size_t)ray * NS + lane * 2);

  // ---------------- coarse pass (4 samples / lane) ----------------
  const float4 z4 = *(const float4*)(z_vals  + (size_t)ray * NC + lane * 4);
  const float4 d4 = *(const float4*)(density + (size_t)ray * NC + lane * 4);
  const float4 fA = *(const float4*)(feature + (size_t)ray * NC * 3 + lane * 12);
  const float4 fB = *(const float4*)(feature + (size_t)ray * NC * 3 + lane * 12 + 4);
  const float4 fC = *(const float4*)(feature + (size_t)ray * NC * 3 + lane * 12 + 8);

  *(float4*)(&zv[wid][lane * 4]) = z4;

  const float znext = wshl1(z4.x);           // lane l gets lane l+1's z4.x
  const float dl0 = z4.y - z4.x;
  const float dl1 = z4.z - z4.y;
  const float dl2 = z4.w - z4.z;
  const float dl3 = (lane == 63) ? FARV : (znext - z4.w);

  const float e0 = __expf(-d4.x * dl0);
  const float e1 = __expf(-d4.y * dl1);
  const float e2 = __expf(-d4.z * dl2);
  const float e3 = __expf(-d4.w * dl3);

  const float p1 = e0, p2 = e0 * e1, p3 = p2 * e2, ptot = p3 * e3;
  const float incl = scan_incl_mul(ptot);
  const float Tb = wshr1(incl, 1.0f);        // exclusive product, lane0 = 1

  const float w0 = Tb *      (1.0f - e0) + 1e-10f;
  const float w1 = Tb * p1 * (1.0f - e1) + 1e-10f;
  const float w2 = Tb * p2 * (1.0f - e2) + 1e-10f;
  const float w3 = Tb * p3 * (1.0f - e3) + 1e-10f;

  // feature layout per lane: fA={f0.xyz,f1.x} fB={f1.yz,f2.xy} fC={f2.z,f3.xyz}
  float fx = w0 * fA.x + w1 * fA.w + w2 * fB.z + w3 * fC.y;
  float fy = w0 * fA.y + w1 * fB.x + w2 * fB.w + w3 * fC.z;
  float fz = w0 * fA.z + w1 * fB.y + w2 * fC.x + w3 * fC.w;
  float dep = w0 * z4.x + w1 * z4.y + w2 * z4.z + w3 * z4.w;

  // ---------------- CDF over w[1:255] ----------------
  const float wn0 = wshl1(w0);               // next lane's w0 (lane63 guarded)
  const bool l63 = (lane == 63);
  const float m0 = w1 + 1e-5f;
  const float m1 = w2 + 1e-5f;
  const float m2 = l63 ? 0.0f : (w3 + 1e-5f);
  const float m3 = l63 ? 0.0f : (wn0 + 1e-5f);
  const float c1 = m0 + m1;
  const float c2 = c1 + m2;
  const float c3 = c2 + m3;
  const float inclS = scan_incl_add(c3);
  const float Sb = wshr1(inclS, 0.0f);       // exclusive sum = cdf[4*lane] (unnorm)
  const float total = __int_as_float(__builtin_amdgcn_readlane(__float_as_int(inclS), 63));
  const float inv = 1.0f / total;

  *(float4*)(&cdfs[wid][4 * lane]) =
      make_float4(Sb * inv, (Sb + m0) * inv, (Sb + c1) * inv, (Sb + c2) * inv);
  cdfg[wid][lane] = Sb * inv;                // group head cdf[4*lane]

  // ---------------- sort the u's (rank of s == rank of u; s monotone in u) ----
  float v0 = uu.x, v1 = uu.y;
  bitonic_sort128(v0, v1, lane);             // sorted elems 2*lane, 2*lane+1

  // ---------------- importance sampling on sorted u's (2 / lane) ----------------
#pragma unroll
  for (int t = 0; t < 2; ++t) {
    const float u = t ? v1 : v0;
    // 6-level search over 64 group heads: last g with cdf[4g] <= u
    int g = 0;
#pragma unroll
    for (int st = 32; st; st >>= 1) {
      const int cand = g + st;               // <= 63
      if (cdfg[wid][cand] <= u) g = cand;
    }
    const float4 f4 = *(const float4*)(&cdfs[wid][4 * g]);
    const float nxt = cdfs[wid][(4 * g + 4 < 256) ? 4 * g + 4 : 255];
    const int ind = 4 * g + 1 + ((u >= f4.y) ? 1 : 0) + ((u >= f4.z) ? 1 : 0)
                              + ((u >= f4.w) ? 1 : 0);           // upper_bound
    const int below = ind - 1;
    const int r = ind - 4 * g;                                   // 1..4
    const float cb = (r == 1) ? f4.x : (r == 2) ? f4.y : (r == 3) ? f4.z : f4.w;
    float ca = (r == 1) ? f4.y : (r == 2) ? f4.z : (r == 3) ? f4.w : nxt;
    if (ind > 254) ca = f4.z;                // clamp above to 254 (unreachable guard)
    const float zb0 = zv[wid][below];
    const float zb1 = zv[wid][below + 1];
    const float zb2 = zv[wid][(below + 2 < 256) ? below + 2 : 255];
    const float bb = 0.5f * (zb0 + zb1);
    const float ba = 0.5f * (zb1 + zb2);
    float den = ca - cb;
    den = (den < 1e-5f) ? 1.0f : den;
    const float tt = (u - cb) / den;
    const float s = bb + tt * (ba - bb);
    // insertion position among coarse z: s in [zv[below], zv[below+2]]
    int u_ = below + 1 + ((s >= zb1) ? 1 : 0) + ((s >= zb2) ? 1 : 0);
    const int up = (u_ > 255) ? 255 : u_;
    atomicAdd(&Hh[wid][up], 1);
    // among-samples rank == sorted index; scatter into padded zf
    const int si = up + 2 * lane + t;
    zfr[si + (si >> 5)] = s;
  }

  // z ranks: i + inclusive-prefix of histogram at i
  const int4 h4 = *(const int4*)(&Hh[wid][4 * lane]);
  const int t0 = h4.x;
  const int t1 = t0 + h4.y;
  const int t2 = t1 + h4.z;
  const int t3 = t2 + h4.w;
  const int inclH = scan_incl_addi(t3);
  const int Hb = wshr1i(inclH);              // exclusive, lane0 = 0

  {
    const int i0 = 4 * lane + 0 + Hb + t0;
    const int i1 = 4 * lane + 1 + Hb + t1;
    const int i2 = 4 * lane + 2 + Hb + t2;
    const int i3 = 4 * lane + 3 + Hb + t3;
    zfr[i0 + (i0 >> 5)] = z4.x;
    zfr[i1 + (i1 >> 5)] = z4.y;
    zfr[i2 + (i2 >> 5)] = z4.z;
    zfr[i3 + (i3 >> 5)] = z4.w;
  }

  // ---------------- fine pass (6 samples / lane, padded reads) ----------------
  const int p0 = 6 * lane;
  float zq[7];
  {
    const float2 a = *(const float2*)(zfr + p0     + (p0 >> 5));
    const float2 b = *(const float2*)(zfr + p0 + 2 + ((p0 + 2) >> 5));
    const float2 c = *(const float2*)(zfr + p0 + 4 + ((p0 + 4) >> 5));
    zq[0] = a.x; zq[1] = a.y; zq[2] = b.x; zq[3] = b.y; zq[4] = c.x; zq[5] = c.y;
    zq[6] = (lane < 63) ? zfr[p0 + 6 + ((p0 + 6) >> 5)] : 0.0f;
  }

  float dlf[6];
#pragma unroll
  for (int j = 0; j < 5; ++j) dlf[j] = zq[j + 1] - zq[j];
  dlf[5] = (lane == 63) ? FARV : (zq[6] - zq[5]);

  const float* fd = fine_density + (size_t)ray * NF + p0;
  const float2 q0 = *(const float2*)(fd);
  const float2 q1 = *(const float2*)(fd + 2);
  const float2 q2 = *(const float2*)(fd + 4);
  const float fdv[6] = {q0.x, q0.y, q1.x, q1.y, q2.x, q2.y};

  float ee[6];
#pragma unroll
  for (int j = 0; j < 6; ++j) ee[j] = __expf(-fdv[j] * dlf[j]);

  float P[6];
  P[0] = 1.0f;
#pragma unroll
  for (int j = 1; j < 6; ++j) P[j] = P[j - 1] * ee[j - 1];
  const float ftot = P[5] * ee[5];

  const float incF = scan_incl_mul(ftot);
  const float Tb2 = wshr1(incF, 1.0f);

  float wfv[6];
  float fdep = 0.0f;
#pragma unroll
  for (int j = 0; j < 6; ++j) {
    wfv[j] = Tb2 * P[j] * (1.0f - ee[j]) + 1e-10f;
    fdep += wfv[j] * zq[j];
  }

  // keep the padded zf reads above ordered before the unpadded wf writes below
  __builtin_amdgcn_sched_barrier(0);

  // store wf UNPADDED into zf (zf fully consumed; wave-private)
  zfr[p0 + 0] = wfv[0];
  zfr[p0 + 1] = wfv[1];
  zfr[p0 + 2] = wfv[2];
  zfr[p0 + 3] = wfv[3];
  zfr[p0 + 4] = wfv[4];
  zfr[p0 + 5] = wfv[5];

  // ---------------- feature accumulation over ALL 384 samples ----------------
  // samples 0..255: 4/lane, float4 loads
  const float4 wq = *(const float4*)(zfr + 4 * lane);   // aligned, conflict-free
  const float* fb = fine_feature + (size_t)ray * (NF * 3) + lane * 12;
  const float4 ga = *(const float4*)(fb);
  const float4 gb = *(const float4*)(fb + 4);
  const float4 gc = *(const float4*)(fb + 8);
  // sample 4l+0: ga.xyz; 4l+1: ga.w,gb.x,gb.y; 4l+2: gb.z,gb.w,gc.x; 4l+3: gc.y,gc.z,gc.w
  float gx = wq.x * ga.x + wq.y * ga.w + wq.z * gb.z + wq.w * gc.y;
  float gy = wq.x * ga.y + wq.y * gb.x + wq.z * gb.w + wq.w * gc.z;
  float gz = wq.x * ga.z + wq.y * gb.y + wq.z * gc.x + wq.w * gc.w;

  // samples 256..383: 2/lane, float2 loads
  const float2 wt2 = *(const float2*)(zfr + 256 + 2 * lane);
  const float* fb2 = fine_feature + (size_t)ray * (NF * 3) + 768 + lane * 6;
  const float2 qa = *(const float2*)(fb2);
  const float2 qb = *(const float2*)(fb2 + 2);
  const float2 qc = *(const float2*)(fb2 + 4);
  // sample 256+2l: qa.x,qa.y,qb.x ; sample 257+2l: qb.y,qc.x,qc.y
  gx += wt2.x * qa.x + wt2.y * qb.y;
  gy += wt2.x * qa.y + wt2.y * qc.x;
  gz += wt2.x * qb.x + wt2.y * qc.y;

  // ---------------- reductions (DPP, result in lane 63) + output ----------------
  fx   = scan_incl_add(fx);
  fy   = scan_incl_add(fy);
  fz   = scan_incl_add(fz);
  dep  = scan_incl_add(dep);
  gx   = scan_incl_add(gx);
  gy   = scan_incl_add(gy);
  gz   = scan_incl_add(gz);
  fdep = scan_incl_add(fdep);

  if (lane == 63) {
    float* o = out + (size_t)ray * 8;
    *(float4*)(o)     = make_float4(fx, fy, fz, dep);
    *(float4*)(o + 4) = make_float4(gx, gy, gz, fdep);
  }
}

extern "C" void kernel_launch(void* const* d_in, const int* in_sizes, int n_in,
                              void* d_out, int out_size, void* d_ws, size_t ws_size,
                              hipStream_t stream) {
  const float* z_vals       = (const float*)d_in[0];
  const float* density      = (const float*)d_in[1];
  const float* feature      = (const float*)d_in[2];
  const float* fine_density = (const float*)d_in[3];
  const float* fine_feature = (const float*)d_in[4];
  const float* u_rand       = (const float*)d_in[5];
  float* out = (float*)d_out;

  const int B = in_sizes[0] / NC;       // 65536
  dim3 grid(B / RPB), block(RPB * 64);
  hipLaunchKernelGGL(vr_kernel, grid, block, 0, stream,
                     z_vals, density, feature, fine_density, fine_feature,
                     u_rand, out);
}